// Round 4
// baseline (114.138 us; speedup 1.0000x reference)
//
#include <hip/hip_runtime.h>
#include <math.h>

#define N_NODES 50000
#define DEG 16
#define E_EDGES (N_NODES * DEG)
#define FIN 128
#define FTOT 192   // 2*FQK + FV
#define FQK 64
#define FV 64
#define H 8

typedef __attribute__((ext_vector_type(8))) short short8;
typedef __attribute__((ext_vector_type(4))) float float4v;

__device__ inline unsigned short f2bf(float f) {
    unsigned int u = __float_as_uint(f);
    unsigned int r = u + 0x7fffu + ((u >> 16) & 1u);  // RNE
    return (unsigned short)(r >> 16);
}
__device__ inline float bf2f(unsigned short b) {
    return __uint_as_float(((unsigned int)b) << 16);
}
__device__ inline float bflo(unsigned int w) { return __uint_as_float(w << 16); }
__device__ inline float bfhi(unsigned int w) { return __uint_as_float(w & 0xffff0000u); }

#define LDB 136   // 128 + 8 bf16 pad (row stride of the Wt LDS image)
#define LDC 194   // 192 + 2 bf16 pad for the epilogue transpose

// ---------- prep: Wt (padded LDS image) [n][LDB], n<192, k<128 ----------
__global__ void wt_prep(const float* __restrict__ W, unsigned short* __restrict__ Wt) {
    int t = blockIdx.x * 256 + threadIdx.x;
    if (t >= FIN * FTOT) return;
    int k = t / FTOT, n = t % FTOT;          // coalesced read of W
    Wt[n * LDB + k] = f2bf(W[t]);
}

// ---------- GEMM: qkv(bf16, kv-interleaved) = x @ W via MFMA ----------
// Block: 256 thr = 4 waves, 64 rows. Full K=128, full N=192 per block.
__global__ __launch_bounds__(256) void gemm_qkv(const float* __restrict__ x,
                                                const unsigned short* __restrict__ Wt,
                                                unsigned short* __restrict__ qkv) {
    __shared__ unsigned short Bt[FTOT * LDB];           // 52224 B
    unsigned short* Ct = Bt;                            // reused after MFMAs
    const int tid = threadIdx.x;

    // flat copy of the padded Wt image: 3264 uint4 chunks
#pragma unroll
    for (int i = 0; i < 13; i++) {
        int c = tid + i * 256;
        if (c < (FTOT * LDB) / 8)
            *(uint4*)(&Bt[c * 8]) = *(const uint4*)(Wt + c * 8);
    }

    const int wave = tid >> 6, lane = tid & 63;
    const int m = lane & 15, q = lane >> 4;
    const int row = blockIdx.x * 64 + wave * 16 + m;
    const int rowc = min(row, N_NODES - 1);

    // A fragments: lane holds x[row][ s*32 + q*8 .. +7 ]
    short8 a[4];
    const float* xr = x + rowc * FIN;
#pragma unroll
    for (int s = 0; s < 4; s++) {
        float4v f0 = *(const float4v*)(xr + s * 32 + q * 8);
        float4v f1 = *(const float4v*)(xr + s * 32 + q * 8 + 4);
        short8 av;
        av[0] = (short)f2bf(f0.x); av[1] = (short)f2bf(f0.y);
        av[2] = (short)f2bf(f0.z); av[3] = (short)f2bf(f0.w);
        av[4] = (short)f2bf(f1.x); av[5] = (short)f2bf(f1.y);
        av[6] = (short)f2bf(f1.z); av[7] = (short)f2bf(f1.w);
        a[s] = av;
    }
    __syncthreads();

    float4v acc[12];
#pragma unroll
    for (int ct = 0; ct < 12; ct++) acc[ct] = (float4v){0.f, 0.f, 0.f, 0.f};
#pragma unroll
    for (int ct = 0; ct < 12; ct++) {
#pragma unroll
        for (int s = 0; s < 4; s++) {
            short8 b = *(const short8*)(&Bt[(ct * 16 + m) * LDB + s * 32 + q * 8]);
            acc[ct] = __builtin_amdgcn_mfma_f32_16x16x32_bf16(a[s], b, acc[ct], 0, 0, 0);
        }
    }
    __syncthreads();   // all Bt reads done; safe to reuse as Ct

    // transpose into interleaved-layout LDS tile (q pre-scaled)
    const int lrow0 = wave * 16 + q * 4;
#pragma unroll
    for (int ct = 0; ct < 12; ct++) {
        const int col = ct * 16 + m;
        int off; float scale;
        if (col < FQK)          { off = col;                      scale = 0.35355339059327373f; }
        else if (col < 2 * FQK) { off = 64 + 2 * (col - 64);      scale = 1.f; }  // k
        else                    { off = 64 + 2 * (col - 128) + 1; scale = 1.f; }  // v
#pragma unroll
        for (int i = 0; i < 4; i++)
            Ct[(lrow0 + i) * LDC + off] = f2bf(acc[ct][i] * scale);
    }
    __syncthreads();

    // coalesced store: 64 rows x 96 dwords
    unsigned int* qg = (unsigned int*)qkv;
    const int base = blockIdx.x * 64;
#pragma unroll
    for (int i = 0; i < 24; i++) {
        int l = tid + i * 256;
        int r = l / 96, dw = l - r * 96;
        if (base + r < N_NODES)
            qg[(size_t)(base + r) * 96 + dw] = *(const unsigned int*)(&Ct[r * LDC + 2 * dw]);
    }
}

// ---------- attention: one wave/node; 4 quarter-waves each own 4 edges ----------
// lane = 16*quarter + l; lane owns kv-pair slots 4l..4l+3 (head h = l>>1).
__global__ __launch_bounds__(256) void attn(const unsigned short* __restrict__ qkv,
                                            const int* __restrict__ dest,
                                            float* __restrict__ out) {
    const int node = blockIdx.x * 4 + (threadIdx.x >> 6);
    const int lane = threadIdx.x & 63;
    const int quarter = lane >> 4;
    const int l = lane & 15;
    if (node >= N_NODES) return;  // wave-uniform

    // q slots 4l..4l+3 (pre-scaled); broadcast across quarters
    const uint2 qw = *(const uint2*)(qkv + node * FTOT + 4 * l);
    const float q0 = bflo(qw.x), q1 = bfhi(qw.x) ;
    const float q2 = bflo(qw.y), q3 = bfhi(qw.y);

    // this quarter's 4 dest nodes (one 16B load from the shared 64B line)
    const int4 dd = ((const int4*)(dest + (size_t)node * DEG))[quarter];

    uint4 kv[4];
    {
        const int d0 = dd.x, d1 = dd.y, d2 = dd.z, d3 = dd.w;
        kv[0] = *(const uint4*)(qkv + d0 * FTOT + 64 + 8 * l);
        kv[1] = *(const uint4*)(qkv + d1 * FTOT + 64 + 8 * l);
        kv[2] = *(const uint4*)(qkv + d2 * FTOT + 64 + 8 * l);
        kv[3] = *(const uint4*)(qkv + d3 * FTOT + 64 + 8 * l);
    }

    float lg[4];
#pragma unroll
    for (int t = 0; t < 4; t++) {
        float p = q0 * bflo(kv[t].x);
        p = fmaf(q1, bflo(kv[t].y), p);
        p = fmaf(q2, bflo(kv[t].z), p);
        p = fmaf(q3, bflo(kv[t].w), p);
        p += __shfl_xor(p, 1, 64);        // pair (2h, 2h+1): full 8-dim dot
        lg[t] = p;
    }

    // global max per head across all 16 edges
    float m = fmaxf(fmaxf(lg[0], lg[1]), fmaxf(lg[2], lg[3]));
    m = fmaxf(m, __shfl_xor(m, 16, 64));
    m = fmaxf(m, __shfl_xor(m, 32, 64));

    float s = 0.f, o0 = 0.f, o1 = 0.f, o2 = 0.f, o3 = 0.f;
#pragma unroll
    for (int t = 0; t < 4; t++) {
        const float p = __expf(lg[t] - m);
        s += p;
        o0 = fmaf(p, bfhi(kv[t].x), o0);
        o1 = fmaf(p, bfhi(kv[t].y), o1);
        o2 = fmaf(p, bfhi(kv[t].z), o2);
        o3 = fmaf(p, bfhi(kv[t].w), o3);
    }
    // merge the 4 quarters
    s  += __shfl_xor(s, 16, 64);  s  += __shfl_xor(s, 32, 64);
    o0 += __shfl_xor(o0, 16, 64); o0 += __shfl_xor(o0, 32, 64);
    o1 += __shfl_xor(o1, 16, 64); o1 += __shfl_xor(o1, 32, 64);
    o2 += __shfl_xor(o2, 16, 64); o2 += __shfl_xor(o2, 32, 64);
    o3 += __shfl_xor(o3, 16, 64); o3 += __shfl_xor(o3, 32, 64);

    if (quarter == 0) {
        const float inv = 1.0f / s;
        float4 r; r.x = o0 * inv; r.y = o1 * inv; r.z = o2 * inv; r.w = o3 * inv;
        *(float4*)(out + node * 64 + 4 * l) = r;
    }
}

extern "C" void kernel_launch(void* const* d_in, const int* in_sizes, int n_in,
                              void* d_out, int out_size, void* d_ws, size_t ws_size,
                              hipStream_t stream) {
    const float* x = (const float*)d_in[0];
    const float* W = (const float*)d_in[1];
    // d_in[2] = batch (unused by reference)
    const int* ei = (const int*)d_in[3];
    const int* dest = ei + E_EDGES;  // ei[1]
    float* out = (float*)d_out;

    unsigned short* qkv = (unsigned short*)d_ws;                       // 19.2 MB
    unsigned short* Wt  = (unsigned short*)((char*)d_ws + 19200000);   // 52.2 KB (padded image)

    wt_prep<<<(FIN * FTOT + 255) / 256, 256, 0, stream>>>(W, Wt);
    gemm_qkv<<<(N_NODES + 63) / 64, 256, 0, stream>>>(x, Wt, qkv);
    attn<<<(N_NODES + 3) / 4, 256, 0, stream>>>(qkv, dest, out);
}